// Round 4
// baseline (287.647 us; speedup 1.0000x reference)
//
#include <hip/hip_runtime.h>
#include <hip/hip_bf16.h>
#include <math.h>

// Problem dims (fixed by reference)
#define BB 64
#define SS 200
#define TT 32
#define VV 50000
#define EE 128
#define CC 128
#define HH 100
#define G3 300           // 3*H
#define OUTD 104
#define NTREE (BB*SS)    // 12800

typedef __attribute__((ext_vector_type(4))) float f32x4;
typedef _Float16 f16x8 __attribute__((ext_vector_type(8)));

__device__ inline float fast_sigmoid(float x) {
    return __builtin_amdgcn_rcpf(1.f + __builtin_amdgcn_exp2f(-1.4426950408889634f * x));
}
__device__ inline float fast_tanh(float x) {
    return 1.f - 2.f * __builtin_amdgcn_rcpf(1.f + __builtin_amdgcn_exp2f(2.8853900817779268f * x));
}

// LDS-only barrier: waits ds-ops (lgkmcnt) but does NOT drain vmcnt, so in-flight
// global prefetch loads stay outstanding across the barrier (waited at use).
#define BAR() asm volatile("s_waitcnt lgkmcnt(0)\n\ts_barrier" ::: "memory")

// Workspace byte offsets
//   wl    @ 0        : 32768 B   (k1 W_lin fragment image, fp16)
//   k2b   @ 32768    : 163840 B  (k2 W_ih fragment image, fp16)
//   thi   @ 196608   : 3276800 B (tree_vec, fp16)
//   k3b   @ 3473408  : 196608 B  (k3 W_hh fragment image, fp16)
//   gx    @ 3670016  : 30720000 B (fp32)  -- ends at 34.39 MB < ws
//   emb16 @ 3670016  : 12800000 B -- ALIASES gx: k0 writes it, k1 reads it,
//                                   k2 overwrites gx only after k1 completes.
//   pool  @ 0        : 51200 B   -- aliases wl/k2b; k3 writes it AFTER k2 read them.

// ---------------- K0: weight-fragment images + fp16 embedding image (idempotent)
__global__ __launch_bounds__(256) void k0_prep(const float* __restrict__ w_lin,
                                               const float* __restrict__ w_ih_f,
                                               const float* __restrict__ w_ih_b,
                                               const float* __restrict__ w_hh_f,
                                               const float* __restrict__ w_hh_b,
                                               const float* __restrict__ emb,
                                               _Float16* __restrict__ wl,
                                               _Float16* __restrict__ k2b,
                                               _Float16* __restrict__ k3b,
                                               _Float16* __restrict__ emb16) {
    const int tid  = threadIdx.x;
    const int wave = tid >> 6;
    const int lane = tid & 63;
    const int r = lane & 15;
    const int q = lane >> 4;
    if (blockIdx.x == 0) {
        // k1 image: wave w, lane(r,q), nt, kt -> W_lin[n=w*32+nt*16+r][k=kt*32+q*8 ..+8]
#pragma unroll
        for (int nt = 0; nt < 2; ++nt)
#pragma unroll
            for (int kt = 0; kt < 4; ++kt) {
                const int n = wave * 32 + nt * 16 + r;
                const float* src = w_lin + (long)n * EE + kt * 32 + q * 8;
                f16x8 f;
#pragma unroll
                for (int e = 0; e < 8; ++e) f[e] = (_Float16)src[e];
                *(f16x8*)&wl[(size_t)((((wave * 2 + nt) * 4 + kt) * 64) + lane) * 8] = f;
            }
    } else if (blockIdx.x <= 10) {
        // k2 image: nb, wave w, lane(r,q), kt -> W_ih[padded n = nb*64+w*16+r][k=kt*32+q*8]
        const int nb = blockIdx.x - 1;           // 0..9
        const int n = nb * 64 + wave * 16 + r;
        const int dir = (n >= 320) ? 1 : 0;
        const int j = n - dir * 320;
        const int jj = (j < G3) ? j : 0;         // pad rows clamped (results discarded)
        const float* w = dir ? w_ih_b : w_ih_f;
#pragma unroll
        for (int kt = 0; kt < 4; ++kt) {
            const float* src = w + (long)jj * EE + kt * 32 + q * 8;
            f16x8 f;
#pragma unroll
            for (int e = 0; e < 8; ++e) f[e] = (_Float16)src[e];
            *(f16x8*)&k2b[(size_t)((((nb * 4 + wave) * 4 + kt) * 64) + lane) * 8] = f;
        }
    } else if (blockIdx.x <= 14) {
        // k3 image: dw = dir*2 + whalf. 12 tiles x 4 kt per dw.
        // tile t: gate g=t%3, channel block cb=t/3; col r -> channel cc=cb*16+r
        // (valid iff cc<50); W_hh row = g*H + 50*whalf + cc; k = kt*32+q*8+e.
        const int dw = blockIdx.x - 11;          // 0..3
        const int d  = dw >> 1;
        const int wh = dw & 1;
        const float* whh = d ? w_hh_b : w_hh_f;
#pragma unroll
        for (int tt = 0; tt < 3; ++tt) {
            const int t = wave * 3 + tt;         // 0..11
            const int g  = t % 3;
            const int cb = t / 3;
            const int cc = cb * 16 + r;
            const bool nv = (cc < 50);
            const int row = g * HH + 50 * wh + (nv ? cc : 0);
#pragma unroll
            for (int kt = 0; kt < 4; ++kt) {
                f16x8 f;
#pragma unroll
                for (int e = 0; e < 8; ++e) {
                    const int k = kt * 32 + q * 8 + e;
                    f[e] = (_Float16)((nv && k < HH) ? whh[row * HH + k] : 0.f);
                }
                *(f16x8*)&k3b[(size_t)((((dw * 12 + t) * 4 + kt) * 64) + lane) * 8] = f;
            }
        }
    } else {
        // fp16 embedding image: 50000*128 = 6,400,000 elems = 3125 blocks * 2048
        const long base = (long)(blockIdx.x - 15) * 2048 + (long)tid * 8;
        if (base < (long)VV * EE) {
            const float4* s = (const float4*)(emb + base);
            const float4 v0 = s[0], v1 = s[1];
            f16x8 f;
            f[0] = (_Float16)v0.x; f[1] = (_Float16)v0.y;
            f[2] = (_Float16)v0.z; f[3] = (_Float16)v0.w;
            f[4] = (_Float16)v1.x; f[5] = (_Float16)v1.y;
            f[6] = (_Float16)v1.z; f[7] = (_Float16)v1.w;
            *(f16x8*)&emb16[base] = f;
        }
    }
}

// ---------------- K1 (fp16 MFMA): embed-gather (fp16) -> GEMM vs W_lin^T -> bias -> tree-sum -> maxpool
#define K1_TPI 2
#define AROWS (K1_TPI*TT)        // 64
#define LDA 136                  // fp16/row: 128 + 8 pad
#define LDC 132                  // fp32/row: 128 + 4 pad

__global__ __launch_bounds__(256) void k1_mfma(const int* __restrict__ tok,
                                               const _Float16* __restrict__ emb16,
                                               const _Float16* __restrict__ wl,
                                               const float* __restrict__ b_lin,
                                               _Float16* __restrict__ thi) {
    __shared__ __align__(16) _Float16 A_sh[AROWS * LDA];   // 17408 B
    __shared__ __align__(16) float C_sh[AROWS * LDC];      // 33792 B
    __shared__ int tok_sh[AROWS];

    const int tid  = threadIdx.x;
    const int wave = tid >> 6;
    const int lane = tid & 63;
    const int r = lane & 15;
    const int q = lane >> 4;

    // ---- B fragments: 8 coalesced 16B loads from the prebuilt image (no cvt VALU)
    f16x8 bfrag[2][4];
    float bias[2];
#pragma unroll
    for (int nt = 0; nt < 2; ++nt) {
        bias[nt] = b_lin[wave * 32 + nt * 16 + r];
#pragma unroll
        for (int kt = 0; kt < 4; ++kt)
            bfrag[nt][kt] = *(const f16x8*)&wl[(size_t)((((wave * 2 + nt) * 4 + kt) * 64) + lane) * 8];
    }

    const int tree0 = blockIdx.x * K1_TPI;
    if (tid < AROWS) tok_sh[tid] = tok[tree0 * TT + tid];
    __syncthreads();

    // ---- gather fp16 embeddings -> LDS (pure 16B copies, half the global traffic)
#pragma unroll
    for (int i = 0; i < 4; ++i) {
        const int idx = tid + i * 256;       // 0..1023
        const int row = idx >> 4;            // 64 rows
        const int p   = idx & 15;            // 16 x f16x8 = 128 elems
        const f16x8 v = *(const f16x8*)&emb16[(long)tok_sh[row] * EE + p * 8];
        *(f16x8*)&A_sh[row * LDA + p * 8] = v;
    }
    __syncthreads();

    f32x4 acc[4][2];
#pragma unroll
    for (int mt = 0; mt < 4; ++mt)
#pragma unroll
        for (int nt = 0; nt < 2; ++nt) acc[mt][nt] = (f32x4)(0.f);

#pragma unroll
    for (int mt = 0; mt < 4; ++mt) {
        const int m = mt * 16 + r;
        f16x8 afrag[4];
#pragma unroll
        for (int kt = 0; kt < 4; ++kt)
            afrag[kt] = *(const f16x8*)&A_sh[m * LDA + kt * 32 + q * 8];
#pragma unroll
        for (int nt = 0; nt < 2; ++nt)
#pragma unroll
            for (int kt = 0; kt < 4; ++kt)
                acc[mt][nt] = __builtin_amdgcn_mfma_f32_16x16x32_f16(
                    afrag[kt], bfrag[nt][kt], acc[mt][nt], 0, 0, 0);
    }

#pragma unroll
    for (int mt = 0; mt < 4; ++mt)
#pragma unroll
        for (int nt = 0; nt < 2; ++nt) {
            const int col = wave * 32 + nt * 16 + r;
#pragma unroll
            for (int reg = 0; reg < 4; ++reg) {
                const int row = mt * 16 + q * 4 + reg;
                C_sh[row * LDC + col] = acc[mt][nt][reg] + bias[nt];
            }
        }
    __syncthreads();

    // ---- tree-sum + maxpool in registers (descending index = topological order)
    {
        const int t = tid >> 7;
        const int j = tid & 127;
        const float* base = &C_sh[(t * TT) * LDC + j];
        float v[TT];
#pragma unroll
        for (int n = 0; n < TT; ++n) v[n] = base[n * LDC];
        float mx = -1e30f;
#pragma unroll
        for (int n = TT - 1; n >= 1; --n) {
            mx = fmaxf(mx, v[n]);
            v[(n - 1) >> 1] += v[n];
        }
        mx = fmaxf(mx, v[0]);
        thi[(size_t)(tree0 + t) * CC + j] = (_Float16)mx;   // fp32 sums, one fp16 round
    }
}

// ---------------- K2 (fp16 MFMA): gx[dir][m=b*S+s][300] = X @ W_ih^T + b_ih
__global__ __launch_bounds__(256) void k2_mfma(const _Float16* __restrict__ thi,
                                               const _Float16* __restrict__ k2b,
                                               const float* __restrict__ b_ih_f,
                                               const float* __restrict__ b_ih_b,
                                               float* __restrict__ gx) {
    __shared__ __align__(16) _Float16 Ah[32 * LDA];   // 8704 B

    const int tid  = threadIdx.x;
    const int wave = tid >> 6;
    const int lane = tid & 63;
    const int r = lane & 15;
    const int q = lane >> 4;

    const int nb = blockIdx.x % 10;
    const int mb = blockIdx.x / 10;
    const int m0 = mb * 32;
    const int n0 = nb * 64;

    // stage A: 32 rows x 128 fp16 = 512 f16x8; 2 per thread (copy, no conversion)
#pragma unroll
    for (int i = 0; i < 2; ++i) {
        const int idx = tid + i * 256;
        const int row = idx >> 4;
        const int p   = idx & 15;
        f16x8 v = *(const f16x8*)&thi[(size_t)(m0 + row) * CC + p * 8];
        *(f16x8*)&Ah[row * LDA + p * 8] = v;
    }
    // B fragments: 4 coalesced 16B loads
    f16x8 bh[4];
#pragma unroll
    for (int kt = 0; kt < 4; ++kt)
        bh[kt] = *(const f16x8*)&k2b[(size_t)((((nb * 4 + wave) * 4 + kt) * 64) + lane) * 8];
    __syncthreads();

    f32x4 acc[2];
    acc[0] = (f32x4)(0.f); acc[1] = (f32x4)(0.f);
#pragma unroll
    for (int mt = 0; mt < 2; ++mt) {
        const int m = mt * 16 + r;
#pragma unroll
        for (int kt = 0; kt < 4; ++kt) {
            f16x8 a = *(const f16x8*)&Ah[m * LDA + kt * 32 + q * 8];
            acc[mt] = __builtin_amdgcn_mfma_f32_16x16x32_f16(a, bh[kt], acc[mt], 0, 0, 0);
        }
    }

    const int ng  = n0 + wave * 16 + r;
    const int dir = (ng >= 320) ? 1 : 0;
    const int j   = ng - dir * 320;
    const bool valid = (j < G3);
    const float bias = valid ? (dir ? b_ih_b[j] : b_ih_f[j]) : 0.f;
    float* gxd = gx + (long)dir * NTREE * G3;
    if (valid) {
#pragma unroll
        for (int mt = 0; mt < 2; ++mt)
#pragma unroll
            for (int reg = 0; reg < 4; ++reg) {
                const int m = m0 + mt * 16 + q * 4 + reg;
                gxd[(long)m * G3 + j] = acc[mt][reg] + bias;
            }
    }
}

// ---------------- K3 v9: 2 waves per chain, self-aligned gate tiles, prebuilt W_hh.
// vs v7 (88.5 us, 4-wave barrier, 1060 cyc/step) and v8 (120.9 us, 8-wave coupling
// regression): shrink the sync scope. Each wave owns 50 channels = 150 outputs =
// 12 tiles (col r of tile t holds gate t%3 of channel (t/3)*16+r) x 4 k-steps =
// 48 MFMA/wave with 12 independent depth-4 acc chains. Gate extraction = static
// ternaries on q (no shfl, no LDS). Per step: one 2-wave barrier + 100-fp16 h
// exchange. 128 independent blocks (1 chain each), 4-deep named gx prefetch.
__global__ __launch_bounds__(128, 1) void k3_gru(const float* __restrict__ gx,
                                                 const _Float16* __restrict__ k3b,
                                                 const float* __restrict__ b_hh_f,
                                                 const float* __restrict__ b_hh_b,
                                                 float* __restrict__ pool) {
    const int bid = blockIdx.x;   // 0..127
    const int dir = bid & 1;
    const int b   = bid >> 1;
    const int tid = threadIdx.x;  // 0..127
    const int wh   = tid >> 6;    // wave: channel half (0: ch 0-49, 1: ch 50-99)
    const int lane = tid & 63;
    const int r = lane & 15;
    const int q = lane >> 4;

    const float* b_hh = dir ? b_hh_b : b_hh_f;

    __shared__ __align__(16) _Float16 h_sh[2][128];   // [parity][channel]

    // B fragments: 48 coalesced 16B loads from prebuilt image
    const int dw = dir * 2 + wh;
    f16x8 bf[12][4];
#pragma unroll
    for (int t = 0; t < 12; ++t)
#pragma unroll
        for (int kt = 0; kt < 4; ++kt)
            bf[t][kt] = *(const f16x8*)&k3b[(size_t)((((dw * 12 + t) * 4 + kt) * 64) + lane) * 8];

    const int cc = q * 16 + r;           // within-wave channel 0..63
    const bool act = (cc < 50);
    const int c = 50 * wh + cc;          // global channel (valid if act)
    float br = 0.f, bz = 0.f, bn = 0.f;
    if (act) { br = b_hh[c]; bz = b_hh[HH + c]; bn = b_hh[2 * HH + c]; }

    h_sh[0][tid] = (_Float16)0.f;
    h_sh[1][tid] = (_Float16)0.f;

    const int sstep = dir ? -1 : 1;
    const int s0 = dir ? (SS - 1) : 0;
    // lane-local base pointer into this chain's gx rows (valid for act lanes)
    const float* gp = gx + (long)dir * NTREE * G3 + (long)b * SS * G3 + c;

    // 4-deep prefetch, NAMED buffers (indices become literals after full unroll)
    float pxr[4], pxz[4], pxn[4];
    if (act) {
#pragma unroll
        for (int j = 0; j < 4; ++j) {
            const long off = (long)(s0 + j * sstep) * G3;
            pxr[j] = gp[off]; pxz[j] = gp[off + HH]; pxn[j] = gp[off + 2 * HH];
        }
    }
    float hj = 0.f, hmax = -1e30f;
    __syncthreads();

    int s = s0;
    for (int t0 = 0; t0 < SS; t0 += 4) {
#pragma unroll
        for (int j = 0; j < 4; ++j) {
            const int p = j & 1;             // (t0+j)&1, t0 multiple of 4

            f16x8 a[4];
#pragma unroll
            for (int kt = 0; kt < 4; ++kt)
                a[kt] = *(const f16x8*)&h_sh[p][kt * 32 + q * 8];

            f32x4 acc[12];
#pragma unroll
            for (int i = 0; i < 12; ++i) {
                acc[i] = (f32x4)(0.f);
#pragma unroll
                for (int kt = 0; kt < 4; ++kt)
                    acc[i] = __builtin_amdgcn_mfma_f32_16x16x32_f16(a[kt], bf[i][kt], acc[i], 0, 0, 0);
            }
            // lane (q,r) owns channel cc=q*16+r; its gates live at tiles 3q+{0,1,2}
            const float ghr = (q == 0) ? acc[0][0] : (q == 1) ? acc[3][0] : (q == 2) ? acc[6][0] : acc[9][0];
            const float ghz = (q == 0) ? acc[1][0] : (q == 1) ? acc[4][0] : (q == 2) ? acc[7][0] : acc[10][0];
            const float ghn = (q == 0) ? acc[2][0] : (q == 1) ? acc[5][0] : (q == 2) ? acc[8][0] : acc[11][0];

            if (act) {
                const float rg = fast_sigmoid(pxr[j] + ghr + br);
                const float zg = fast_sigmoid(pxz[j] + ghz + bz);
                const float ng = fast_tanh(pxn[j] + rg * (ghn + bn));
                hj = (1.f - zg) * ng + zg * hj;
                h_sh[1 - p][c] = (_Float16)hj;
                hmax = fmaxf(hmax, hj);
                // refill this slot for step t0+j+4 (consumed 4 step-periods from now)
                if (t0 + j + 4 < SS) {
                    const long off = (long)(s + (j + 4) * sstep) * G3;
                    pxr[j] = gp[off]; pxz[j] = gp[off + HH]; pxn[j] = gp[off + 2 * HH];
                }
            }
            BAR();
        }
        s += 4 * sstep;
    }
    if (act) pool[(long)b * (2 * HH) + dir * HH + c] = hmax;
}

// ---------------- K4: out[b][o] = fc_b[o] + pool[b,:] . fc_w[o,:]
__global__ __launch_bounds__(256) void k4_fc(const float* __restrict__ pool,
                                             const float* __restrict__ fc_w,
                                             const float* __restrict__ fc_b,
                                             float* __restrict__ out) {
    const int b = blockIdx.x;
    __shared__ __align__(16) float p_sh[2 * HH];
    const int t = threadIdx.x;
    if (t < 2 * HH) p_sh[t] = pool[(long)b * (2 * HH) + t];
    __syncthreads();
    if (t < OUTD) {
        const float4* wr4 = (const float4*)(fc_w + (long)t * (2 * HH));
        const float4* p4 = (const float4*)p_sh;
        float a0 = 0.f, a1 = 0.f;
#pragma unroll
        for (int k = 0; k < 50; k += 2) {
            float4 w0 = wr4[k],   p0 = p4[k];
            float4 w1 = wr4[k+1], p1 = p4[k+1];
            a0 += w0.x*p0.x + w0.y*p0.y + w0.z*p0.z + w0.w*p0.w;
            a1 += w1.x*p1.x + w1.y*p1.y + w1.z*p1.z + w1.w*p1.w;
        }
        out[(long)b * OUTD + t] = fc_b[t] + a0 + a1;
    }
}

extern "C" void kernel_launch(void* const* d_in, const int* in_sizes, int n_in,
                              void* d_out, int out_size, void* d_ws, size_t ws_size,
                              hipStream_t stream) {
    const int*   tok    = (const int*)d_in[0];
    const float* emb    = (const float*)d_in[4];
    const float* w_lin  = (const float*)d_in[5];
    const float* b_lin  = (const float*)d_in[6];
    const float* w_ih_f = (const float*)d_in[7];
    const float* w_hh_f = (const float*)d_in[8];
    const float* b_ih_f = (const float*)d_in[9];
    const float* b_hh_f = (const float*)d_in[10];
    const float* w_ih_b = (const float*)d_in[11];
    const float* w_hh_b = (const float*)d_in[12];
    const float* b_ih_b = (const float*)d_in[13];
    const float* b_hh_b = (const float*)d_in[14];
    const float* fc_w   = (const float*)d_in[15];
    const float* fc_b   = (const float*)d_in[16];

    char* wsb = (char*)d_ws;
    _Float16* wl    = (_Float16*)(wsb);             // 32768 B
    _Float16* k2b   = (_Float16*)(wsb + 32768);     // 163840 B
    _Float16* thi   = (_Float16*)(wsb + 196608);    // 3276800 B
    _Float16* k3b   = (_Float16*)(wsb + 3473408);   // 196608 B
    float*    gx    = (float*)(wsb + 3670016);      // 30720000 B (ends 34.39 MB)
    _Float16* emb16 = (_Float16*)(wsb + 3670016);   // aliases gx: k0->k1 use, k2 overwrites
    float*    pool  = (float*)(wsb);                // aliases wl/k2b: k3 runs after k2
    float*    out   = (float*)d_out;

    k0_prep<<<15 + 3125, 256, 0, stream>>>(w_lin, w_ih_f, w_ih_b, w_hh_f, w_hh_b, emb,
                                           wl, k2b, k3b, emb16);
    k1_mfma<<<NTREE / K1_TPI, 256, 0, stream>>>(tok, emb16, wl, b_lin, thi);
    k2_mfma<<<(NTREE / 32) * 10, 256, 0, stream>>>(thi, k2b, b_ih_f, b_ih_b, gx);
    k3_gru <<<2 * BB, 128, 0, stream>>>(gx, k3b, b_hh_f, b_hh_b, pool);
    k4_fc  <<<BB, 256, 0, stream>>>(pool, fc_w, fc_b, out);
}